// Round 1
// baseline (5373.292 us; speedup 1.0000x reference)
//
#include <hip/hip_runtime.h>
#include <hip/hip_bf16.h>
#include <math.h>

// Problem constants (match reference)
#define NND 100000   // nodes
#define EE  200000   // edges
#define LL  3        // layers
#define DD  300      // node dim
#define HH  150      // per-direction message dim

__device__ __forceinline__ float gelu_exact(float z) {
    return 0.5f * z * (1.0f + erff(z * 0.7071067811865475f));
}

// Build Bcat[l][k][j] (k=0..299, j=0..599) from Wr/Wc (each [L, 600, 150]):
//  j in [0,150):   Ar cols -> Wr[l][k][j]          (applied to v[dst], r-dir)
//  j in [150,300): Br cols -> Wr[l][300+k][j-150]  (applied to v[src], r-dir)
//  j in [300,450): Ac cols -> Wc[l][k][j-300]      (applied to v[src], c-dir target side)
//  j in [450,600): Bc cols -> Wc[l][300+k][j-450]  (applied to v[dst], c-dir source side)
__global__ __launch_bounds__(256) void pack_w(
    const float* __restrict__ Wr, const float* __restrict__ Wc,
    float* __restrict__ Bcat)
{
    const int total = LL * DD * 600;
    for (int i = blockIdx.x * 256 + threadIdx.x; i < total; i += gridDim.x * 256) {
        int l = i / (DD * 600);
        int rem = i % (DD * 600);
        int k = rem / 600;
        int j = rem % 600;
        float v;
        if (j < 150)      v = Wr[(size_t)((l * 600) + k) * 150 + j];
        else if (j < 300) v = Wr[(size_t)((l * 600) + 300 + k) * 150 + (j - 150)];
        else if (j < 450) v = Wc[(size_t)((l * 600) + k) * 150 + (j - 300)];
        else              v = Wc[(size_t)((l * 600) + 300 + k) * 150 + (j - 450)];
        Bcat[i] = v;
    }
}

// C[M,Nn] = A[M,K] @ B[K,Nn]   (row-major)
// mode 0: C = acc
// mode 1: C += gelu(acc + bias[col])   (node update, C = v in-place)
__global__ __launch_bounds__(256) void gemm_f32(
    const float* __restrict__ A, const float* __restrict__ B,
    float* __restrict__ C, const float* __restrict__ bias,
    int M, int K, int Nn, int mode)
{
    __shared__ float As[16][65];  // [k][m], +1 pad
    __shared__ float Bs[16][64];  // [k][n]
    const int tid  = threadIdx.x;
    const int brow = blockIdx.y * 64;
    const int bcol = blockIdx.x * 64;
    const int trow = (tid >> 4) << 2;   // (tid/16)*4
    const int tcol = (tid & 15) << 2;   // (tid%16)*4

    float acc[4][4] = {};

    for (int k0 = 0; k0 < K; k0 += 16) {
        // stage A tile 64x16 (4 elems/thread)
        #pragma unroll
        for (int i = 0; i < 4; ++i) {
            int li = tid + i * 256;       // 0..1023
            int r = li >> 4, c = li & 15; // row, k
            int gr = brow + r, gk = k0 + c;
            As[c][r] = (gr < M && gk < K) ? A[(size_t)gr * K + gk] : 0.0f;
        }
        // stage B tile 16x64 (4 elems/thread, coalesced over n)
        #pragma unroll
        for (int i = 0; i < 4; ++i) {
            int li = tid + i * 256;
            int r = li >> 6, c = li & 63; // k, col
            int gk = k0 + r, gc = bcol + c;
            Bs[r][c] = (gk < K && gc < Nn) ? B[(size_t)gk * Nn + gc] : 0.0f;
        }
        __syncthreads();
        #pragma unroll
        for (int kk = 0; kk < 16; ++kk) {
            float a0 = As[kk][trow + 0], a1 = As[kk][trow + 1];
            float a2 = As[kk][trow + 2], a3 = As[kk][trow + 3];
            float b0 = Bs[kk][tcol + 0], b1 = Bs[kk][tcol + 1];
            float b2 = Bs[kk][tcol + 2], b3 = Bs[kk][tcol + 3];
            acc[0][0] += a0 * b0; acc[0][1] += a0 * b1; acc[0][2] += a0 * b2; acc[0][3] += a0 * b3;
            acc[1][0] += a1 * b0; acc[1][1] += a1 * b1; acc[1][2] += a1 * b2; acc[1][3] += a1 * b3;
            acc[2][0] += a2 * b0; acc[2][1] += a2 * b1; acc[2][2] += a2 * b2; acc[2][3] += a2 * b3;
            acc[3][0] += a3 * b0; acc[3][1] += a3 * b1; acc[3][2] += a3 * b2; acc[3][3] += a3 * b3;
        }
        __syncthreads();
    }

    #pragma unroll
    for (int i = 0; i < 4; ++i) {
        int gr = brow + trow + i;
        if (gr >= M) continue;
        #pragma unroll
        for (int j = 0; j < 4; ++j) {
            int gc = bcol + tcol + j;
            if (gc >= Nn) continue;
            size_t idx = (size_t)gr * Nn + gc;
            if (mode == 0) C[idx] = acc[i][j];
            else           C[idx] += gelu_exact(acc[i][j] + bias[gc]);
        }
    }
}

// One wave per edge. P = [N,600] projections: [Ar | Br | Ac | Bc].
// r at dst: gelu(Ar[d] + Br[s] + br);  c at src: gelu(Ac[s] + Bc[d] + bc)
// RC = [N,300]: cols 0..149 = r, 150..299 = c
__global__ __launch_bounds__(256) void edge_kernel(
    const int* __restrict__ src, const int* __restrict__ dst,
    const float* __restrict__ P,
    const float* __restrict__ br, const float* __restrict__ bc,
    float* __restrict__ RC, int E)
{
    int gthread = blockIdx.x * 256 + threadIdx.x;
    int e = gthread >> 6;
    int lane = threadIdx.x & 63;
    if (e >= E) return;
    int s = src[e], d = dst[e];
    const float* Pd = P + (size_t)d * 600;
    const float* Ps = P + (size_t)s * 600;
    float* RCd = RC + (size_t)d * 300;
    float* RCs = RC + (size_t)s * 300;
    for (int h = lane; h < HH; h += 64) {
        float vr = gelu_exact(Pd[h] + Ps[150 + h] + br[h]);
        atomicAdd(&RCd[h], vr);
        float vc = gelu_exact(Ps[300 + h] + Pd[450 + h] + bc[h]);
        atomicAdd(&RCs[150 + h], vc);
    }
}

extern "C" void kernel_launch(void* const* d_in, const int* in_sizes, int n_in,
                              void* d_out, int out_size, void* d_ws, size_t ws_size,
                              hipStream_t stream) {
    const float* x  = (const float*)d_in[0];
    const int*   ei = (const int*)  d_in[1];
    const float* Wr = (const float*)d_in[2];
    const float* br = (const float*)d_in[3];
    const float* Wc = (const float*)d_in[4];
    const float* bc = (const float*)d_in[5];
    const float* Wa = (const float*)d_in[6];
    const float* ba = (const float*)d_in[7];
    float* out = (float*)d_out;

    const size_t P_elems    = (size_t)NND * 600;
    const size_t RC_elems   = (size_t)NND * 300;
    const size_t Bcat_elems = (size_t)LL * DD * 600;
    float* P    = (float*)d_ws;
    float* RC   = P + P_elems;
    float* Bcat = RC + RC_elems;
    const size_t need = (P_elems + RC_elems + Bcat_elems) * sizeof(float);
    if (ws_size < need) return;  // diagnostic: output stays poisoned -> visible fail

    // v = x
    hipMemcpyAsync(out, x, (size_t)NND * DD * sizeof(float),
                   hipMemcpyDeviceToDevice, stream);
    pack_w<<<2110, 256, 0, stream>>>(Wr, Wc, Bcat);

    const int* src = ei;        // edge_index[0]
    const int* dst = ei + EE;   // edge_index[1]

    dim3 gproj((600 + 63) / 64, (NND + 63) / 64);
    dim3 gupd((DD + 63) / 64, (NND + 63) / 64);
    int eblocks = (EE + 3) / 4;  // 4 edges (waves) per 256-thread block

    for (int l = 0; l < LL; ++l) {
        hipMemsetAsync(RC, 0, RC_elems * sizeof(float), stream);
        // P = v @ Bcat_l  -> [Ar | Br | Ac | Bc]
        gemm_f32<<<gproj, 256, 0, stream>>>(out, Bcat + (size_t)l * DD * 600,
                                            P, nullptr, NND, DD, 600, 0);
        // edge gather/scatter
        edge_kernel<<<eblocks, 256, 0, stream>>>(src, dst, P,
                                                 br + (size_t)l * HH,
                                                 bc + (size_t)l * HH, RC, EE);
        // v += gelu(RC @ Wa + ba)
        gemm_f32<<<gupd, 256, 0, stream>>>(RC, Wa, out, ba, NND, DD, DD, 1);
    }
}

// Round 2
// 2025.632 us; speedup vs baseline: 2.6526x; 2.6526x over previous
//
#include <hip/hip_runtime.h>
#include <hip/hip_bf16.h>
#include <math.h>

#define NND 100000   // nodes
#define EE  200000   // edges
#define LL  3        // layers
#define DD  300      // node dim
#define HH  150      // per-direction message dim

#define MPAD 100096  // 782 * 128
#define KP   320     // K padded to multiple of 32
#define NPJ  640     // proj N padded (600 -> 5*128)
#define NUP  384     // update N padded (300 -> 3*128)

typedef __attribute__((ext_vector_type(8))) short bf16x8;
typedef __attribute__((ext_vector_type(4))) float f32x4;

__device__ __forceinline__ float gelu_exact(float z) {
    return 0.5f * z * (1.0f + erff(z * 0.7071067811865475f));
}
__device__ __forceinline__ unsigned short f2bf(float f) {
    union { float fv; unsigned u; } v; v.fv = f;
    unsigned r = v.u + 0x7fff + ((v.u >> 16) & 1);   // RNE (finite inputs)
    return (unsigned short)(r >> 16);
}
__device__ __forceinline__ float bf2f(unsigned short b) {
    union { unsigned u; float fv; } v; v.u = ((unsigned)b) << 16;
    return v.fv;
}

// Pack weights, transposed + padded, to bf16:
//  Bt[l][n][k] (n<640, k<320, stride KP) = Bcat[l][k][n] of round-0, zeros in pads
//  Wat[n][k]   (n<384, k<320)           = Wa[k][n], zeros in pads
__global__ __launch_bounds__(256) void pack_w(
    const float* __restrict__ Wr, const float* __restrict__ Wc,
    const float* __restrict__ Wa,
    unsigned short* __restrict__ Bt, unsigned short* __restrict__ Wat)
{
    int i = blockIdx.x * 256 + threadIdx.x;
    const int btTotal = LL * NPJ * KP;
    if (i < btTotal) {
        int l = i / (NPJ * KP);
        int rem = i % (NPJ * KP);
        int n = rem / KP;
        int k = rem % KP;
        float v = 0.f;
        if (k < DD && n < 600) {
            const float* W = (n < 300) ? Wr : Wc;
            int nn = (n < 300) ? n : n - 300;
            int krow = (nn < 150) ? k : 300 + k;
            int j    = (nn < 150) ? nn : nn - 150;
            v = W[(size_t)l * 600 * 150 + (size_t)krow * 150 + j];
        }
        Bt[i] = f2bf(v);
    } else {
        int i2 = i - btTotal;
        if (i2 < NUP * KP) {
            int n = i2 / KP, k = i2 % KP;
            float v = (n < DD && k < DD) ? Wa[(size_t)k * DD + n] : 0.f;
            Wat[i2] = f2bf(v);
        }
    }
}

#define GLOAD16(gp, lp) __builtin_amdgcn_global_load_lds( \
    (const __attribute__((address_space(1))) unsigned int*)(gp), \
    (__attribute__((address_space(3))) unsigned int*)(lp), 16, 0, 0)

// C[M,N] = A[M,K] @ Bt[N,K]^T.  A fp32 (bf16-converted in staging), Bt bf16.
// MODE 0: P[row*NPJ+col] = bf16(acc)                (proj)
// MODE 1: out[row*DD+col] += gelu(acc + bias[col])  (update, masked to real dims)
template<int MODE>
__global__ __launch_bounds__(256) void gemm_mfma(
    const float* __restrict__ A, int Astride, int Kreal, int Mreal,
    const unsigned short* __restrict__ Bt,
    unsigned short* __restrict__ P,
    float* __restrict__ outv, const float* __restrict__ bias)
{
    __shared__ unsigned short Al[128 * 32];
    __shared__ unsigned short Bl[128 * 32];
    const int tid  = threadIdx.x;
    const int lane = tid & 63;
    const int wid  = tid >> 6;
    const int brow = blockIdx.y * 128;
    const int bcol = blockIdx.x * 128;
    const int wm = (wid >> 1) * 64;
    const int wn = (wid & 1) * 64;

    f32x4 acc[4][4];
    #pragma unroll
    for (int i = 0; i < 4; ++i)
        #pragma unroll
        for (int j = 0; j < 4; ++j)
            #pragma unroll
            for (int r = 0; r < 4; ++r) acc[i][j][r] = 0.f;

    for (int k0 = 0; k0 < KP; k0 += 32) {
        // ---- B stage: global_load_lds (16B), source pre-swizzled (rule 21)
        #pragma unroll
        for (int i = 0; i < 2; ++i) {
            int cb = wid * 128 + i * 64;          // wave-uniform chunk base
            int ci = cb + lane;
            int row = ci >> 2, pc = ci & 3;
            int c = pc ^ ((row >> 1) & 3);        // inverse swizzle on SOURCE
            const unsigned short* gp = Bt + (size_t)(bcol + row) * KP + k0 + c * 8;
            GLOAD16(gp, &Bl[cb * 8]);
        }
        // ---- A stage: fp32 -> bf16 regs -> swizzled ds_write_b128
        #pragma unroll
        for (int i = 0; i < 2; ++i) {
            int ci = tid + i * 256;
            int row = ci >> 2, c = ci & 3;
            int gr = brow + row;
            int gk = k0 + c * 8;
            unsigned short tmp[8];
            if (gr < Mreal && gk < Kreal) {
                if (gk + 8 <= Kreal) {
                    const float4* p = (const float4*)(A + (size_t)gr * Astride + gk);
                    float4 f0 = p[0], f1 = p[1];
                    tmp[0] = f2bf(f0.x); tmp[1] = f2bf(f0.y);
                    tmp[2] = f2bf(f0.z); tmp[3] = f2bf(f0.w);
                    tmp[4] = f2bf(f1.x); tmp[5] = f2bf(f1.y);
                    tmp[6] = f2bf(f1.z); tmp[7] = f2bf(f1.w);
                } else {
                    #pragma unroll
                    for (int j = 0; j < 8; ++j)
                        tmp[j] = (gk + j < Kreal)
                                 ? f2bf(A[(size_t)gr * Astride + gk + j]) : 0;
                }
            } else {
                #pragma unroll
                for (int j = 0; j < 8; ++j) tmp[j] = 0;
            }
            int phys = row * 32 + ((c ^ ((row >> 1) & 3)) * 8);  // shorts
            *((bf16x8*)&Al[phys]) = *((bf16x8*)tmp);
        }
        __syncthreads();

        // ---- fragments + 16 MFMA
        bf16x8 af[4], bfr[4];
        #pragma unroll
        for (int mi = 0; mi < 4; ++mi) {
            int row = wm + mi * 16 + (lane & 15);
            int phys = row * 32 + (((lane >> 4) ^ ((row >> 1) & 3)) * 8);
            af[mi] = *((const bf16x8*)&Al[phys]);
        }
        #pragma unroll
        for (int nj = 0; nj < 4; ++nj) {
            int row = wn + nj * 16 + (lane & 15);
            int phys = row * 32 + (((lane >> 4) ^ ((row >> 1) & 3)) * 8);
            bfr[nj] = *((const bf16x8*)&Bl[phys]);
        }
        #pragma unroll
        for (int mi = 0; mi < 4; ++mi)
            #pragma unroll
            for (int nj = 0; nj < 4; ++nj)
                acc[mi][nj] = __builtin_amdgcn_mfma_f32_16x16x32_bf16(
                    af[mi], bfr[nj], acc[mi][nj], 0, 0, 0);
        __syncthreads();
    }

    // ---- epilogue: C/D layout col=lane&15, row=(lane>>4)*4+r  [m89]
    #pragma unroll
    for (int mi = 0; mi < 4; ++mi) {
        #pragma unroll
        for (int nj = 0; nj < 4; ++nj) {
            int col   = bcol + wn + nj * 16 + (lane & 15);
            int rbase = brow + wm + mi * 16 + ((lane >> 4) << 2);
            #pragma unroll
            for (int r = 0; r < 4; ++r) {
                int row = rbase + r;
                float v = acc[mi][nj][r];
                if (MODE == 0) {
                    P[(size_t)row * NPJ + col] = f2bf(v);
                } else {
                    if (row < NND && col < DD) {
                        size_t idx = (size_t)row * DD + col;
                        outv[idx] = outv[idx] + gelu_exact(v + bias[col]);
                    }
                }
            }
        }
    }
}

// One wave per edge; P bf16 [MPAD][NPJ] = [Ar | Br | Ac | Bc] (cols 0/150/300/450).
// r at dst: gelu(Ar[d]+Br[s]+br) ; c at src: gelu(Ac[s]+Bc[d]+bc)
__global__ __launch_bounds__(256) void edge_kernel(
    const int* __restrict__ src, const int* __restrict__ dst,
    const unsigned short* __restrict__ P,
    const float* __restrict__ br, const float* __restrict__ bc,
    float* __restrict__ RC)
{
    int e = (blockIdx.x * 256 + threadIdx.x) >> 6;
    int lane = threadIdx.x & 63;
    if (e >= EE) return;
    int s = src[e], d = dst[e];
    const unsigned short* Pd = P + (size_t)d * NPJ;
    const unsigned short* Ps = P + (size_t)s * NPJ;
    float* RCd = RC + (size_t)d * KP;
    float* RCs = RC + (size_t)s * KP;
    for (int h = lane; h < HH; h += 64) {
        float vr = gelu_exact(bf2f(Pd[h]) + bf2f(Ps[150 + h]) + br[h]);
        atomicAdd(&RCd[h], vr);
        float vc = gelu_exact(bf2f(Ps[300 + h]) + bf2f(Pd[450 + h]) + bc[h]);
        atomicAdd(&RCs[150 + h], vc);
    }
}

extern "C" void kernel_launch(void* const* d_in, const int* in_sizes, int n_in,
                              void* d_out, int out_size, void* d_ws, size_t ws_size,
                              hipStream_t stream) {
    const float* x  = (const float*)d_in[0];
    const int*   ei = (const int*)  d_in[1];
    const float* Wr = (const float*)d_in[2];
    const float* br = (const float*)d_in[3];
    const float* Wc = (const float*)d_in[4];
    const float* bc = (const float*)d_in[5];
    const float* Wa = (const float*)d_in[6];
    const float* ba = (const float*)d_in[7];
    float* out = (float*)d_out;

    const size_t P_elems   = (size_t)MPAD * NPJ;   // bf16
    const size_t RC_elems  = (size_t)MPAD * KP;    // fp32
    const size_t Bt_elems  = (size_t)LL * NPJ * KP;
    const size_t Wat_elems = (size_t)NUP * KP;

    unsigned short* P   = (unsigned short*)d_ws;
    float*          RC  = (float*)(P + P_elems);
    unsigned short* Bt  = (unsigned short*)(RC + RC_elems);
    unsigned short* Wat = Bt + Bt_elems;
    const size_t need = P_elems * 2 + RC_elems * 4 + (Bt_elems + Wat_elems) * 2;
    if (ws_size < need) return;  // visible fail (output stays poisoned)

    // v = x
    hipMemcpyAsync(out, x, (size_t)NND * DD * sizeof(float),
                   hipMemcpyDeviceToDevice, stream);
    pack_w<<<(LL * NPJ * KP + NUP * KP) / (256 * 256) + 1 > 2880 ? 2881 : 2880,
             256, 0, stream>>>(Wr, Wc, Wa, Bt, Wat);

    const int* src = ei;
    const int* dst = ei + EE;

    dim3 gproj(NPJ / 128, MPAD / 128);
    dim3 gupd (NUP / 128, MPAD / 128);
    int eblocks = (EE * 64) / 256;

    for (int l = 0; l < LL; ++l) {
        hipMemsetAsync(RC, 0, RC_elems * sizeof(float), stream);
        // P = bf16( v @ Bt_l^T )
        gemm_mfma<0><<<gproj, 256, 0, stream>>>(
            out, DD, DD, NND, Bt + (size_t)l * NPJ * KP, P, nullptr, nullptr);
        // edge gather/scatter
        edge_kernel<<<eblocks, 256, 0, stream>>>(
            src, dst, P, br + (size_t)l * HH, bc + (size_t)l * HH, RC);
        // v += gelu(RC @ Wat^T + ba)
        gemm_mfma<1><<<gupd, 256, 0, stream>>>(
            RC, KP, KP, MPAD, Wat, nullptr, out, ba);
    }
}

// Round 3
// 1685.123 us; speedup vs baseline: 3.1887x; 1.2021x over previous
//
#include <hip/hip_runtime.h>
#include <hip/hip_bf16.h>
#include <math.h>

#define NND 100000   // nodes
#define EE  200000   // edges
#define LL  3        // layers
#define DD  300      // node dim
#define HH  150      // per-direction message dim

#define MPAD 100096  // 782 * 128
#define KP   320     // K padded (multiple of 32)
#define NPJ  640     // proj N padded
#define NUP  384     // update N padded
#define NTK  (KP / 32)

typedef __attribute__((ext_vector_type(8))) short bf16x8;
typedef __attribute__((ext_vector_type(4))) float f32x4;

__device__ __forceinline__ float gelu_exact(float z) {
    return 0.5f * z * (1.0f + erff(z * 0.7071067811865475f));
}
__device__ __forceinline__ unsigned short f2bf(float f) {
    union { float fv; unsigned u; } v; v.fv = f;
    unsigned r = v.u + 0x7fff + ((v.u >> 16) & 1);   // RNE (finite inputs)
    return (unsigned short)(r >> 16);
}
__device__ __forceinline__ float bf2f(unsigned short b) {
    union { unsigned u; float fv; } v; v.u = ((unsigned)b) << 16;
    return v.fv;
}

// Bt[l][n][k] (n<640,k<320) = logical Bcat[l][k][n], zero pads, bf16
// Wat[n][k]   (n<384,k<320) = Wa[k][n], zero pads, bf16
__global__ __launch_bounds__(256) void pack_w(
    const float* __restrict__ Wr, const float* __restrict__ Wc,
    const float* __restrict__ Wa,
    unsigned short* __restrict__ Bt, unsigned short* __restrict__ Wat)
{
    int i = blockIdx.x * 256 + threadIdx.x;
    const int btTotal = LL * NPJ * KP;
    if (i < btTotal) {
        int l = i / (NPJ * KP);
        int rem = i % (NPJ * KP);
        int n = rem / KP;
        int k = rem % KP;
        float v = 0.f;
        if (k < DD && n < 600) {
            const float* W = (n < 300) ? Wr : Wc;
            int nn = (n < 300) ? n : n - 300;
            int krow = (nn < 150) ? k : 300 + k;
            int j    = (nn < 150) ? nn : nn - 150;
            v = W[(size_t)l * 600 * 150 + (size_t)krow * 150 + j];
        }
        Bt[i] = f2bf(v);
    } else {
        int i2 = i - btTotal;
        if (i2 < NUP * KP) {
            int n = i2 / KP, k = i2 % KP;
            float v = (n < DD && k < DD) ? Wa[(size_t)k * DD + n] : 0.f;
            Wat[i2] = f2bf(v);
        }
    }
}

// vbf[MPAD][KP] = bf16(x), zero pads. 8 elems/thread.
__global__ __launch_bounds__(256) void init_vbf(
    const float* __restrict__ x, unsigned short* __restrict__ vbf)
{
    int idx = blockIdx.x * 256 + threadIdx.x;       // chunk of 8
    int row = idx / (KP / 8);
    int gk  = (idx % (KP / 8)) * 8;
    if (row >= MPAD) return;
    unsigned short tmp[8];
    if (row < NND && gk < DD) {
        if (gk + 8 <= DD) {
            const float4* p = (const float4*)(x + (size_t)row * DD + gk);
            float4 f0 = p[0], f1 = p[1];
            tmp[0] = f2bf(f0.x); tmp[1] = f2bf(f0.y);
            tmp[2] = f2bf(f0.z); tmp[3] = f2bf(f0.w);
            tmp[4] = f2bf(f1.x); tmp[5] = f2bf(f1.y);
            tmp[6] = f2bf(f1.z); tmp[7] = f2bf(f1.w);
        } else {
            #pragma unroll
            for (int j = 0; j < 8; ++j)
                tmp[j] = (gk + j < DD) ? f2bf(x[(size_t)row * DD + gk + j]) : 0;
        }
    } else {
        #pragma unroll
        for (int j = 0; j < 8; ++j) tmp[j] = 0;
    }
    *((bf16x8*)&vbf[(size_t)row * KP + gk]) = *((bf16x8*)tmp);
}

#define GLOAD16(gp, lp) __builtin_amdgcn_global_load_lds( \
    (const __attribute__((address_space(1))) unsigned int*)(gp), \
    (__attribute__((address_space(3))) unsigned int*)(lp), 16, 0, 0)

// Swizzle: row of 32 bf16 = 4 chunks of 16B; chunk c stored at c ^ ((row>>1)&3).
#define STAGE_LDS(buf, dst, srcbase, rowoff, k0) do {                        \
    _Pragma("unroll")                                                        \
    for (int i_ = 0; i_ < 2; ++i_) {                                         \
        int cb_ = wid * 128 + i_ * 64;                                       \
        int ci_ = cb_ + lane;                                                \
        int row_ = ci_ >> 2, pc_ = ci_ & 3;                                  \
        int c_ = pc_ ^ ((row_ >> 1) & 3);                                    \
        GLOAD16(srcbase + (size_t)(rowoff + row_) * KP + (k0) + c_ * 8,      \
                &dst[buf][cb_ * 8]);                                         \
    } } while (0)

// C[128x128 tiles] = A[M,KP] @ Bt[N,KP]^T
// MODE 0: A = vbf (bf16, global_load_lds), P[row*NPJ+col] = bf16(acc)
// MODE 1: A = RC (fp32, reg-stage+convert), out += gelu(acc+bias), vbf = bf16(out)
template<int MODE>
__global__ __launch_bounds__(256) void gemm_mfma(
    const void* __restrict__ Av,
    const unsigned short* __restrict__ Bt,
    unsigned short* __restrict__ P,
    float* __restrict__ outv, unsigned short* __restrict__ vbf,
    const float* __restrict__ bias)
{
    __shared__ unsigned short Al[2][128 * 32];
    __shared__ unsigned short Bl[2][128 * 32];
    const int tid  = threadIdx.x;
    const int lane = tid & 63;
    const int wid  = tid >> 6;

    // bijective XCD swizzle (m204)
    const int gx   = gridDim.x;
    const int nwg  = gx * gridDim.y;
    const int flat = blockIdx.y * gx + blockIdx.x;
    const int q = nwg >> 3, r = nwg & 7;
    const int xcd = flat & 7, off = flat >> 3;
    const int lid = (xcd < r ? xcd * (q + 1) : r * (q + 1) + (xcd - r) * q) + off;
    const int brow = (lid / gx) * 128;
    const int bcol = (lid % gx) * 128;

    const int wm = (wid >> 1) * 64;
    const int wn = (wid & 1) * 64;

    const unsigned short* Ab = (const unsigned short*)Av;  // MODE 0
    const float*          Af = (const float*)Av;           // MODE 1
    // MODE 1 per-thread A-stage coords
    const int r0 = tid >> 2,          c0 = tid & 3;
    const int r1 = (tid + 256) >> 2,  c1 = tid & 3;

    f32x4 acc[4][4];
    #pragma unroll
    for (int i = 0; i < 4; ++i)
        #pragma unroll
        for (int j = 0; j < 4; ++j)
            #pragma unroll
            for (int rr = 0; rr < 4; ++rr) acc[i][j][rr] = 0.f;

    // ---- prologue: stage tile 0 into buf 0
    STAGE_LDS(0, Bl, Bt, bcol, 0);
    if (MODE == 0) {
        STAGE_LDS(0, Al, Ab, brow, 0);
    } else {
        const float4* p0 = (const float4*)(Af + (size_t)(brow + r0) * KP + c0 * 8);
        const float4* p1 = (const float4*)(Af + (size_t)(brow + r1) * KP + c1 * 8);
        float4 a00 = p0[0], a01 = p0[1], a10 = p1[0], a11 = p1[1];
        unsigned short t0[8] = { f2bf(a00.x), f2bf(a00.y), f2bf(a00.z), f2bf(a00.w),
                                 f2bf(a01.x), f2bf(a01.y), f2bf(a01.z), f2bf(a01.w) };
        unsigned short t1[8] = { f2bf(a10.x), f2bf(a10.y), f2bf(a10.z), f2bf(a10.w),
                                 f2bf(a11.x), f2bf(a11.y), f2bf(a11.z), f2bf(a11.w) };
        *((bf16x8*)&Al[0][r0 * 32 + ((c0 ^ ((r0 >> 1) & 3)) * 8)]) = *((bf16x8*)t0);
        *((bf16x8*)&Al[0][r1 * 32 + ((c1 ^ ((r1 >> 1) & 3)) * 8)]) = *((bf16x8*)t1);
    }
    __syncthreads();

    int cur = 0;
    for (int t = 0; t < NTK; ++t) {
        const int k0n = (t + 1) * 32;
        float4 a00, a01, a10, a11;
        if (t + 1 < NTK) {
            STAGE_LDS(cur ^ 1, Bl, Bt, bcol, k0n);
            if (MODE == 0) {
                STAGE_LDS(cur ^ 1, Al, Ab, brow, k0n);
            } else {
                const float4* p0 = (const float4*)(Af + (size_t)(brow + r0) * KP + k0n + c0 * 8);
                const float4* p1 = (const float4*)(Af + (size_t)(brow + r1) * KP + k0n + c1 * 8);
                a00 = p0[0]; a01 = p0[1]; a10 = p1[0]; a11 = p1[1];
            }
        }

        // fragments from buf[cur] + 16 MFMA
        bf16x8 af[4], bfr[4];
        #pragma unroll
        for (int mi = 0; mi < 4; ++mi) {
            int row = wm + mi * 16 + (lane & 15);
            af[mi] = *((const bf16x8*)&Al[cur][row * 32 + (((lane >> 4) ^ ((row >> 1) & 3)) * 8)]);
        }
        #pragma unroll
        for (int nj = 0; nj < 4; ++nj) {
            int row = wn + nj * 16 + (lane & 15);
            bfr[nj] = *((const bf16x8*)&Bl[cur][row * 32 + (((lane >> 4) ^ ((row >> 1) & 3)) * 8)]);
        }
        __builtin_amdgcn_s_setprio(1);
        #pragma unroll
        for (int mi = 0; mi < 4; ++mi)
            #pragma unroll
            for (int nj = 0; nj < 4; ++nj)
                acc[mi][nj] = __builtin_amdgcn_mfma_f32_16x16x32_bf16(
                    af[mi], bfr[nj], acc[mi][nj], 0, 0, 0);
        __builtin_amdgcn_s_setprio(0);

        if (MODE == 1 && t + 1 < NTK) {
            unsigned short t0[8] = { f2bf(a00.x), f2bf(a00.y), f2bf(a00.z), f2bf(a00.w),
                                     f2bf(a01.x), f2bf(a01.y), f2bf(a01.z), f2bf(a01.w) };
            unsigned short t1[8] = { f2bf(a10.x), f2bf(a10.y), f2bf(a10.z), f2bf(a10.w),
                                     f2bf(a11.x), f2bf(a11.y), f2bf(a11.z), f2bf(a11.w) };
            *((bf16x8*)&Al[cur ^ 1][r0 * 32 + ((c0 ^ ((r0 >> 1) & 3)) * 8)]) = *((bf16x8*)t0);
            *((bf16x8*)&Al[cur ^ 1][r1 * 32 + ((c1 ^ ((r1 >> 1) & 3)) * 8)]) = *((bf16x8*)t1);
        }
        __syncthreads();
        cur ^= 1;
    }

    // ---- epilogue: C/D layout col=lane&15, row=(lane>>4)*4+r  [m89]
    #pragma unroll
    for (int mi = 0; mi < 4; ++mi) {
        #pragma unroll
        for (int nj = 0; nj < 4; ++nj) {
            int col   = bcol + wn + nj * 16 + (lane & 15);
            int rbase = brow + wm + mi * 16 + ((lane >> 4) << 2);
            #pragma unroll
            for (int rr = 0; rr < 4; ++rr) {
                int row = rbase + rr;
                float v = acc[mi][nj][rr];
                if (MODE == 0) {
                    P[(size_t)row * NPJ + col] = f2bf(v);
                } else {
                    if (row < NND && col < DD) {
                        size_t idx = (size_t)row * DD + col;
                        float nv = outv[idx] + gelu_exact(v + bias[col]);
                        outv[idx] = nv;
                        vbf[(size_t)row * KP + col] = f2bf(nv);
                    }
                }
            }
        }
    }
}

// One wave per edge; P bf16 [MPAD][NPJ] = [Ar | Br | Ac | Bc] (col base 0/150/300/450).
__global__ __launch_bounds__(256) void edge_kernel(
    const int* __restrict__ src, const int* __restrict__ dst,
    const unsigned short* __restrict__ P,
    const float* __restrict__ br, const float* __restrict__ bc,
    float* __restrict__ RC)
{
    int e = (blockIdx.x * 256 + threadIdx.x) >> 6;
    int lane = threadIdx.x & 63;
    if (e >= EE) return;
    int s = src[e], d = dst[e];
    const unsigned short* Pd = P + (size_t)d * NPJ;
    const unsigned short* Ps = P + (size_t)s * NPJ;
    float* RCd = RC + (size_t)d * KP;
    float* RCs = RC + (size_t)s * KP;
    #pragma unroll
    for (int h = lane; h < HH; h += 64) {
        float vr = gelu_exact(bf2f(Pd[h]) + bf2f(Ps[150 + h]) + br[h]);
        atomicAdd(&RCd[h], vr);
        float vc = gelu_exact(bf2f(Ps[300 + h]) + bf2f(Pd[450 + h]) + bc[h]);
        atomicAdd(&RCs[150 + h], vc);
    }
}

extern "C" void kernel_launch(void* const* d_in, const int* in_sizes, int n_in,
                              void* d_out, int out_size, void* d_ws, size_t ws_size,
                              hipStream_t stream) {
    const float* x  = (const float*)d_in[0];
    const int*   ei = (const int*)  d_in[1];
    const float* Wr = (const float*)d_in[2];
    const float* br = (const float*)d_in[3];
    const float* Wc = (const float*)d_in[4];
    const float* bc = (const float*)d_in[5];
    const float* Wa = (const float*)d_in[6];
    const float* ba = (const float*)d_in[7];
    float* out = (float*)d_out;

    const size_t P_elems   = (size_t)MPAD * NPJ;   // bf16
    const size_t RC_elems  = (size_t)MPAD * KP;    // fp32
    const size_t V_elems   = (size_t)MPAD * KP;    // bf16
    const size_t Bt_elems  = (size_t)LL * NPJ * KP;
    const size_t Wat_elems = (size_t)NUP * KP;

    unsigned short* P   = (unsigned short*)d_ws;
    float*          RC  = (float*)(P + P_elems);
    unsigned short* vbf = (unsigned short*)(RC + RC_elems);
    unsigned short* Bt  = vbf + V_elems;
    unsigned short* Wat = Bt + Bt_elems;
    const size_t need = P_elems * 2 + RC_elems * 4 + (V_elems + Bt_elems + Wat_elems) * 2;
    if (ws_size < need) return;  // visible fail (output stays poisoned)

    hipMemcpyAsync(out, x, (size_t)NND * DD * sizeof(float),
                   hipMemcpyDeviceToDevice, stream);
    pack_w<<<2880, 256, 0, stream>>>(Wr, Wc, Wa, Bt, Wat);
    init_vbf<<<(int)((V_elems / 8 + 255) / 256), 256, 0, stream>>>(x, vbf);

    const int* src = ei;
    const int* dst = ei + EE;

    dim3 gproj(NPJ / 128, MPAD / 128);
    dim3 gupd (NUP / 128, MPAD / 128);
    int eblocks = (EE * 64) / 256;

    for (int l = 0; l < LL; ++l) {
        hipMemsetAsync(RC, 0, RC_elems * sizeof(float), stream);
        // P = bf16( v @ Bt_l^T )
        gemm_mfma<0><<<gproj, 256, 0, stream>>>(
            vbf, Bt + (size_t)l * NPJ * KP, P, nullptr, nullptr, nullptr);
        // edge gather/scatter
        edge_kernel<<<eblocks, 256, 0, stream>>>(
            src, dst, P, br + (size_t)l * HH, bc + (size_t)l * HH, RC);
        // v += gelu(RC @ Wat^T + ba); vbf = bf16(v)
        gemm_mfma<1><<<gupd, 256, 0, stream>>>(
            RC, Wat, nullptr, out, vbf, ba);
    }
}

// Round 4
// 1356.817 us; speedup vs baseline: 3.9602x; 1.2420x over previous
//
#include <hip/hip_runtime.h>
#include <hip/hip_bf16.h>
#include <math.h>

#define NND 100000   // nodes
#define EE  200000   // edges
#define LL  3        // layers
#define DD  300      // node dim
#define HH  150      // per-direction message dim

#define MPAD 100096  // 782 * 128
#define KP   320     // K padded (multiple of 32)
#define NPJ  640     // proj N padded
#define NUP  384     // update N padded
#define NTK  (KP / 32)

#define NB   49          // scan blocks (2048 elems each)
#define SCN  (NB * 2048) // 100352 >= MPAD+1

typedef __attribute__((ext_vector_type(8))) short bf16x8;
typedef __attribute__((ext_vector_type(4))) float f32x4;

__device__ __forceinline__ float gelu_exact(float z) {
    return 0.5f * z * (1.0f + erff(z * 0.7071067811865475f));
}
__device__ __forceinline__ unsigned short f2bf(float f) {
    union { float fv; unsigned u; } v; v.fv = f;
    unsigned r = v.u + 0x7fff + ((v.u >> 16) & 1);   // RNE (finite inputs)
    return (unsigned short)(r >> 16);
}
__device__ __forceinline__ float bf2f(unsigned short b) {
    union { unsigned u; float fv; } v; v.u = ((unsigned)b) << 16;
    return v.fv;
}

// ---------------- weight packing ----------------
__global__ __launch_bounds__(256) void pack_w(
    const float* __restrict__ Wr, const float* __restrict__ Wc,
    const float* __restrict__ Wa,
    unsigned short* __restrict__ Bt, unsigned short* __restrict__ Wat)
{
    int i = blockIdx.x * 256 + threadIdx.x;
    const int btTotal = LL * NPJ * KP;
    if (i < btTotal) {
        int l = i / (NPJ * KP);
        int rem = i % (NPJ * KP);
        int n = rem / KP;
        int k = rem % KP;
        float v = 0.f;
        if (k < DD && n < 600) {
            const float* W = (n < 300) ? Wr : Wc;
            int nn = (n < 300) ? n : n - 300;
            int krow = (nn < 150) ? k : 300 + k;
            int j    = (nn < 150) ? nn : nn - 150;
            v = W[(size_t)l * 600 * 150 + (size_t)krow * 150 + j];
        }
        Bt[i] = f2bf(v);
    } else {
        int i2 = i - btTotal;
        if (i2 < NUP * KP) {
            int n = i2 / KP, k = i2 % KP;
            float v = (n < DD && k < DD) ? Wa[(size_t)k * DD + n] : 0.f;
            Wat[i2] = f2bf(v);
        }
    }
}

// vbf[MPAD][KP] = bf16(x), zero pads
__global__ __launch_bounds__(256) void init_vbf(
    const float* __restrict__ x, unsigned short* __restrict__ vbf)
{
    int idx = blockIdx.x * 256 + threadIdx.x;       // chunk of 8
    int row = idx / (KP / 8);
    int gk  = (idx % (KP / 8)) * 8;
    if (row >= MPAD) return;
    unsigned short tmp[8];
    if (row < NND && gk < DD) {
        if (gk + 8 <= DD) {
            const float4* p = (const float4*)(x + (size_t)row * DD + gk);
            float4 f0 = p[0], f1 = p[1];
            tmp[0] = f2bf(f0.x); tmp[1] = f2bf(f0.y);
            tmp[2] = f2bf(f0.z); tmp[3] = f2bf(f0.w);
            tmp[4] = f2bf(f1.x); tmp[5] = f2bf(f1.y);
            tmp[6] = f2bf(f1.z); tmp[7] = f2bf(f1.w);
        } else {
            #pragma unroll
            for (int j = 0; j < 8; ++j)
                tmp[j] = (gk + j < DD) ? f2bf(x[(size_t)row * DD + gk + j]) : 0;
        }
    } else {
        #pragma unroll
        for (int j = 0; j < 8; ++j) tmp[j] = 0;
    }
    *((bf16x8*)&vbf[(size_t)row * KP + gk]) = *((bf16x8*)tmp);
}

// ---------------- CSR build ----------------
__global__ __launch_bounds__(256) void hist_deg(
    const int* __restrict__ src, const int* __restrict__ dst,
    int* __restrict__ deg)  // deg[0][SCN] by dst, deg[1][SCN] by src
{
    int e = blockIdx.x * 256 + threadIdx.x;
    if (e >= EE) return;
    atomicAdd(&deg[dst[e]], 1);
    atomicAdd(&deg[SCN + src[e]], 1);
}

// block-level exclusive scan: 2048 elems/block, 8/thread
__global__ __launch_bounds__(256) void scanA(
    const int* __restrict__ deg, int* __restrict__ off, int* __restrict__ bsum)
{
    __shared__ int ls[256];
    const int t = threadIdx.x, row = blockIdx.y;
    const int base = blockIdx.x * 2048 + t * 8;
    const int* dg = deg + (size_t)row * SCN + base;
    int v[8];
    #pragma unroll
    for (int j = 0; j < 8; ++j) v[j] = dg[j];
    int tot = 0;
    #pragma unroll
    for (int j = 0; j < 8; ++j) tot += v[j];
    ls[t] = tot;
    __syncthreads();
    #pragma unroll
    for (int d = 1; d < 256; d <<= 1) {
        int tv = (t >= d) ? ls[t - d] : 0;
        __syncthreads();
        ls[t] += tv;
        __syncthreads();
    }
    int run = ls[t] - tot;  // exclusive prefix
    int* op = off + (size_t)row * SCN + base;
    #pragma unroll
    for (int j = 0; j < 8; ++j) { op[j] = run; run += v[j]; }
    if (t == 255) bsum[row * 64 + blockIdx.x] = ls[255];
}

__global__ __launch_bounds__(256) void scanB(int* __restrict__ bsum)
{
    if (threadIdx.x < 2) {
        int row = threadIdx.x, c = 0;
        for (int i = 0; i < NB; ++i) {
            int tv = bsum[row * 64 + i];
            bsum[row * 64 + i] = c;
            c += tv;
        }
    }
}

__global__ __launch_bounds__(256) void scanC(
    int* __restrict__ off, const int* __restrict__ bsum, int* __restrict__ cur)
{
    const int t = threadIdx.x, row = blockIdx.y;
    const int base = blockIdx.x * 2048 + t * 8;
    const int add = bsum[row * 64 + blockIdx.x];
    int* op = off + (size_t)row * SCN + base;
    int* cp = cur + (size_t)row * SCN + base;
    #pragma unroll
    for (int j = 0; j < 8; ++j) {
        int v = op[j] + add;
        op[j] = v;
        cp[j] = v;
    }
}

__global__ __launch_bounds__(256) void fill_adj(
    const int* __restrict__ src, const int* __restrict__ dst,
    int* __restrict__ cur, int* __restrict__ adj)  // adj[0][EE] dst-CSR, adj[1][EE] src-CSR
{
    int e = blockIdx.x * 256 + threadIdx.x;
    if (e >= EE) return;
    int s = src[e], d = dst[e];
    int pd = atomicAdd(&cur[d], 1);
    adj[pd] = s;
    int ps = atomicAdd(&cur[SCN + s], 1);
    adj[EE + ps] = d;
}

// ---------------- aggregation (no atomics) ----------------
// dir 0 (r at node n): sum over incoming edges: gelu(P[n][h] + P[s][150+h] + br[h])
//   -> RC[n][h],        h in [0,150)
// dir 1 (c at node n): sum over outgoing edges: gelu(P[n][300+h] + P[d][450+h] + bc[h])
//   -> RC[n][150+h],    plus zeros for pad cols [300,320)
__global__ __launch_bounds__(256) void aggregate(
    const int* __restrict__ off, const int* __restrict__ adj,
    const unsigned short* __restrict__ P,
    const float* __restrict__ br, const float* __restrict__ bc,
    unsigned short* __restrict__ RC)
{
    const int n    = blockIdx.x * 4 + (threadIdx.x >> 6);
    const int dir  = blockIdx.y;
    const int lane = threadIdx.x & 63;
    const int h0 = lane, h1 = lane + 64, h2 = lane + 128;

    unsigned short* outrow = RC + (size_t)n * KP + dir * 150;
    if (n >= NND) {  // zero pad rows
        outrow[h0] = 0; outrow[h1] = 0;
        if (h2 < (dir ? 170 : 150)) outrow[h2] = 0;
        return;
    }

    const int* offp = off + (size_t)dir * SCN;
    const int* adjp = adj + (size_t)dir * EE;
    const float* bias = dir ? bc : br;
    const unsigned short* own = P + (size_t)n * NPJ + dir * 300;
    const int poff = dir ? 450 : 150;

    float o0 = bf2f(own[h0]) + bias[h0];
    float o1 = bf2f(own[h1]) + bias[h1];
    float o2 = (h2 < 150) ? bf2f(own[h2]) + bias[h2] : 0.f;

    float s0 = 0.f, s1 = 0.f, s2 = 0.f;
    int beg = offp[n], end = offp[n + 1];
    for (int i = beg; i < end; ++i) {
        const unsigned short* pp = P + (size_t)adjp[i] * NPJ + poff;
        s0 += gelu_exact(o0 + bf2f(pp[h0]));
        s1 += gelu_exact(o1 + bf2f(pp[h1]));
        if (h2 < 150) s2 += gelu_exact(o2 + bf2f(pp[h2]));
    }
    outrow[h0] = f2bf(s0);
    outrow[h1] = f2bf(s1);
    if (h2 < 150)                outrow[h2] = f2bf(s2);
    else if (dir == 1 && h2 < 170) outrow[h2] = 0;   // K-pad cols 300..319
}

// ---------------- MFMA GEMM ----------------
#define GLOAD16(gp, lp) __builtin_amdgcn_global_load_lds( \
    (const __attribute__((address_space(1))) unsigned int*)(gp), \
    (__attribute__((address_space(3))) unsigned int*)(lp), 16, 0, 0)

#define STAGE_LDS(buf, dst, srcbase, rowoff, k0) do {                        \
    _Pragma("unroll")                                                        \
    for (int i_ = 0; i_ < 2; ++i_) {                                         \
        int cb_ = wid * 128 + i_ * 64;                                       \
        int ci_ = cb_ + lane;                                                \
        int row_ = ci_ >> 2, pc_ = ci_ & 3;                                  \
        int c_ = pc_ ^ ((row_ >> 1) & 3);                                    \
        GLOAD16(srcbase + (size_t)(rowoff + row_) * KP + (k0) + c_ * 8,      \
                &dst[buf][cb_ * 8]);                                         \
    } } while (0)

// C[128x128 tiles] = A[M,KP](bf16) @ Bt[N,KP]^T(bf16)
// MODE 0: P[row*NPJ+col] = bf16(acc)
// MODE 1: out[row*DD+col] += gelu(acc + bias[col]); vbf = bf16(out)
template<int MODE>
__global__ __launch_bounds__(256) void gemm_mfma(
    const unsigned short* __restrict__ Ab,
    const unsigned short* __restrict__ Bt,
    unsigned short* __restrict__ P,
    float* __restrict__ outv, unsigned short* __restrict__ vbf,
    const float* __restrict__ bias)
{
    __shared__ unsigned short Al[2][128 * 32];
    __shared__ unsigned short Bl[2][128 * 32];
    const int tid  = threadIdx.x;
    const int lane = tid & 63;
    const int wid  = tid >> 6;

    // bijective XCD swizzle (m204)
    const int gx   = gridDim.x;
    const int nwg  = gx * gridDim.y;
    const int flat = blockIdx.y * gx + blockIdx.x;
    const int q = nwg >> 3, r = nwg & 7;
    const int xcd = flat & 7, off = flat >> 3;
    const int lid = (xcd < r ? xcd * (q + 1) : r * (q + 1) + (xcd - r) * q) + off;
    const int brow = (lid / gx) * 128;
    const int bcol = (lid % gx) * 128;

    const int wm = (wid >> 1) * 64;
    const int wn = (wid & 1) * 64;

    f32x4 acc[4][4];
    #pragma unroll
    for (int i = 0; i < 4; ++i)
        #pragma unroll
        for (int j = 0; j < 4; ++j)
            #pragma unroll
            for (int rr = 0; rr < 4; ++rr) acc[i][j][rr] = 0.f;

    STAGE_LDS(0, Bl, Bt, bcol, 0);
    STAGE_LDS(0, Al, Ab, brow, 0);
    __syncthreads();

    int cur = 0;
    for (int t = 0; t < NTK; ++t) {
        if (t + 1 < NTK) {
            STAGE_LDS(cur ^ 1, Bl, Bt, bcol, (t + 1) * 32);
            STAGE_LDS(cur ^ 1, Al, Ab, brow, (t + 1) * 32);
        }
        bf16x8 af[4], bfr[4];
        #pragma unroll
        for (int mi = 0; mi < 4; ++mi) {
            int row = wm + mi * 16 + (lane & 15);
            af[mi] = *((const bf16x8*)&Al[cur][row * 32 + (((lane >> 4) ^ ((row >> 1) & 3)) * 8)]);
        }
        #pragma unroll
        for (int nj = 0; nj < 4; ++nj) {
            int row = wn + nj * 16 + (lane & 15);
            bfr[nj] = *((const bf16x8*)&Bl[cur][row * 32 + (((lane >> 4) ^ ((row >> 1) & 3)) * 8)]);
        }
        __builtin_amdgcn_s_setprio(1);
        #pragma unroll
        for (int mi = 0; mi < 4; ++mi)
            #pragma unroll
            for (int nj = 0; nj < 4; ++nj)
                acc[mi][nj] = __builtin_amdgcn_mfma_f32_16x16x32_bf16(
                    af[mi], bfr[nj], acc[mi][nj], 0, 0, 0);
        __builtin_amdgcn_s_setprio(0);
        __syncthreads();
        cur ^= 1;
    }

    // epilogue: C/D layout col=lane&15, row=(lane>>4)*4+r  [m89]
    #pragma unroll
    for (int mi = 0; mi < 4; ++mi) {
        #pragma unroll
        for (int nj = 0; nj < 4; ++nj) {
            int col   = bcol + wn + nj * 16 + (lane & 15);
            int rbase = brow + wm + mi * 16 + ((lane >> 4) << 2);
            #pragma unroll
            for (int rr = 0; rr < 4; ++rr) {
                int row = rbase + rr;
                float v = acc[mi][nj][rr];
                if (MODE == 0) {
                    P[(size_t)row * NPJ + col] = f2bf(v);
                } else {
                    if (row < NND && col < DD) {
                        size_t idx = (size_t)row * DD + col;
                        float nv = outv[idx] + gelu_exact(v + bias[col]);
                        outv[idx] = nv;
                        vbf[(size_t)row * KP + col] = f2bf(nv);
                    }
                }
            }
        }
    }
}

extern "C" void kernel_launch(void* const* d_in, const int* in_sizes, int n_in,
                              void* d_out, int out_size, void* d_ws, size_t ws_size,
                              hipStream_t stream) {
    const float* x  = (const float*)d_in[0];
    const int*   ei = (const int*)  d_in[1];
    const float* Wr = (const float*)d_in[2];
    const float* br = (const float*)d_in[3];
    const float* Wc = (const float*)d_in[4];
    const float* bc = (const float*)d_in[5];
    const float* Wa = (const float*)d_in[6];
    const float* ba = (const float*)d_in[7];
    float* out = (float*)d_out;

    const size_t P_elems   = (size_t)MPAD * NPJ;   // bf16
    const size_t RC_elems  = (size_t)MPAD * KP;    // bf16
    const size_t V_elems   = (size_t)MPAD * KP;    // bf16
    const size_t Bt_elems  = (size_t)LL * NPJ * KP;
    const size_t Wat_elems = (size_t)NUP * KP;

    unsigned short* P   = (unsigned short*)d_ws;
    unsigned short* RC  = P + P_elems;
    unsigned short* vbf = RC + RC_elems;
    unsigned short* Bt  = vbf + V_elems;
    unsigned short* Wat = Bt + Bt_elems;
    // int region (4-byte aligned: even # of ushorts precedes)
    int* deg  = (int*)(Wat + Wat_elems);
    int* off  = deg + 2 * SCN;
    int* curp = off + 2 * SCN;
    int* adj  = curp + 2 * SCN;
    int* bsum = adj + 2 * EE;
    const size_t need = (char*)(bsum + 128) - (char*)d_ws;
    if (ws_size < need) return;  // visible fail (output stays poisoned)

    hipMemcpyAsync(out, x, (size_t)NND * DD * sizeof(float),
                   hipMemcpyDeviceToDevice, stream);
    pack_w<<<2880, 256, 0, stream>>>(Wr, Wc, Wa, Bt, Wat);
    init_vbf<<<(int)((V_elems / 8 + 255) / 256), 256, 0, stream>>>(x, vbf);

    const int* src = ei;
    const int* dst = ei + EE;

    // ---- CSR build (once per call, reused by all layers)
    hipMemsetAsync(deg, 0, 2 * SCN * sizeof(int), stream);
    hist_deg<<<(EE + 255) / 256, 256, 0, stream>>>(src, dst, deg);
    scanA<<<dim3(NB, 2), 256, 0, stream>>>(deg, off, bsum);
    scanB<<<1, 256, 0, stream>>>(bsum);
    scanC<<<dim3(NB, 2), 256, 0, stream>>>(off, bsum, curp);
    fill_adj<<<(EE + 255) / 256, 256, 0, stream>>>(src, dst, curp, adj);

    dim3 gproj(NPJ / 128, MPAD / 128);
    dim3 gupd (NUP / 128, MPAD / 128);
    dim3 gagg (MPAD / 4, 2);

    for (int l = 0; l < LL; ++l) {
        // P = bf16( v @ Bt_l^T )
        gemm_mfma<0><<<gproj, 256, 0, stream>>>(
            vbf, Bt + (size_t)l * NPJ * KP, P, nullptr, nullptr, nullptr);
        // RC = segment-sums (no atomics)
        aggregate<<<gagg, 256, 0, stream>>>(
            off, adj, P, br + (size_t)l * HH, bc + (size_t)l * HH, RC);
        // v += gelu(RC @ Wat^T + ba); vbf = bf16(v)
        gemm_mfma<1><<<gupd, 256, 0, stream>>>(
            RC, Wat, nullptr, out, vbf, ba);
    }
}

// Round 5
// 1284.048 us; speedup vs baseline: 4.1847x; 1.0567x over previous
//
#include <hip/hip_runtime.h>
#include <hip/hip_bf16.h>
#include <math.h>

#define NND 100000   // nodes
#define EE  200000   // edges
#define LL  3        // layers
#define DD  300      // node dim
#define HH  150      // per-direction message dim

#define MPAD 100096  // 782 * 128
#define KP   320     // K padded (multiple of 32)
#define NPJ  640     // proj N padded
#define NUP  384     // update N padded
#define NTK  (KP / 32)

#define NB   49          // scan blocks (2048 elems each)
#define SCN  (NB * 2048) // 100352 >= MPAD+1

typedef __attribute__((ext_vector_type(8))) short bf16x8;
typedef __attribute__((ext_vector_type(4))) short bf16x4;
typedef __attribute__((ext_vector_type(4))) float f32x4;

__device__ __forceinline__ float gelu_exact(float z) {
    return 0.5f * z * (1.0f + erff(z * 0.7071067811865475f));
}
__device__ __forceinline__ unsigned short f2bf(float f) {
    union { float fv; unsigned u; } v; v.fv = f;
    unsigned r = v.u + 0x7fff + ((v.u >> 16) & 1);   // RNE (finite inputs)
    return (unsigned short)(r >> 16);
}
__device__ __forceinline__ float bf2f(unsigned short b) {
    union { unsigned u; float fv; } v; v.u = ((unsigned)b) << 16;
    return v.fv;
}

// ---------------- weight packing ----------------
__global__ __launch_bounds__(256) void pack_w(
    const float* __restrict__ Wr, const float* __restrict__ Wc,
    const float* __restrict__ Wa,
    unsigned short* __restrict__ Bt, unsigned short* __restrict__ Wat)
{
    int i = blockIdx.x * 256 + threadIdx.x;
    const int btTotal = LL * NPJ * KP;
    if (i < btTotal) {
        int l = i / (NPJ * KP);
        int rem = i % (NPJ * KP);
        int n = rem / KP;
        int k = rem % KP;
        float v = 0.f;
        if (k < DD && n < 600) {
            const float* W = (n < 300) ? Wr : Wc;
            int nn = (n < 300) ? n : n - 300;
            int krow = (nn < 150) ? k : 300 + k;
            int j    = (nn < 150) ? nn : nn - 150;
            v = W[(size_t)l * 600 * 150 + (size_t)krow * 150 + j];
        }
        Bt[i] = f2bf(v);
    } else {
        int i2 = i - btTotal;
        if (i2 < NUP * KP) {
            int n = i2 / KP, k = i2 % KP;
            float v = (n < DD && k < DD) ? Wa[(size_t)k * DD + n] : 0.f;
            Wat[i2] = f2bf(v);
        }
    }
}

// vbf[MPAD][KP] = bf16(x), zero pads
__global__ __launch_bounds__(256) void init_vbf(
    const float* __restrict__ x, unsigned short* __restrict__ vbf)
{
    int idx = blockIdx.x * 256 + threadIdx.x;       // chunk of 8
    int row = idx / (KP / 8);
    int gk  = (idx % (KP / 8)) * 8;
    if (row >= MPAD) return;
    unsigned short tmp[8];
    if (row < NND && gk < DD) {
        if (gk + 8 <= DD) {
            const float4* p = (const float4*)(x + (size_t)row * DD + gk);
            float4 f0 = p[0], f1 = p[1];
            tmp[0] = f2bf(f0.x); tmp[1] = f2bf(f0.y);
            tmp[2] = f2bf(f0.z); tmp[3] = f2bf(f0.w);
            tmp[4] = f2bf(f1.x); tmp[5] = f2bf(f1.y);
            tmp[6] = f2bf(f1.z); tmp[7] = f2bf(f1.w);
        } else {
            #pragma unroll
            for (int j = 0; j < 8; ++j)
                tmp[j] = (gk + j < DD) ? f2bf(x[(size_t)row * DD + gk + j]) : 0;
        }
    } else {
        #pragma unroll
        for (int j = 0; j < 8; ++j) tmp[j] = 0;
    }
    *((bf16x8*)&vbf[(size_t)row * KP + gk]) = *((bf16x8*)tmp);
}

// ---------------- CSR build ----------------
__global__ __launch_bounds__(256) void hist_deg(
    const int* __restrict__ src, const int* __restrict__ dst,
    int* __restrict__ deg)
{
    int e = blockIdx.x * 256 + threadIdx.x;
    if (e >= EE) return;
    atomicAdd(&deg[dst[e]], 1);
    atomicAdd(&deg[SCN + src[e]], 1);
}

__global__ __launch_bounds__(256) void scanA(
    const int* __restrict__ deg, int* __restrict__ off, int* __restrict__ bsum)
{
    __shared__ int ls[256];
    const int t = threadIdx.x, row = blockIdx.y;
    const int base = blockIdx.x * 2048 + t * 8;
    const int* dg = deg + (size_t)row * SCN + base;
    int v[8];
    #pragma unroll
    for (int j = 0; j < 8; ++j) v[j] = dg[j];
    int tot = 0;
    #pragma unroll
    for (int j = 0; j < 8; ++j) tot += v[j];
    ls[t] = tot;
    __syncthreads();
    #pragma unroll
    for (int d = 1; d < 256; d <<= 1) {
        int tv = (t >= d) ? ls[t - d] : 0;
        __syncthreads();
        ls[t] += tv;
        __syncthreads();
    }
    int run = ls[t] - tot;
    int* op = off + (size_t)row * SCN + base;
    #pragma unroll
    for (int j = 0; j < 8; ++j) { op[j] = run; run += v[j]; }
    if (t == 255) bsum[row * 64 + blockIdx.x] = ls[255];
}

__global__ __launch_bounds__(256) void scanB(int* __restrict__ bsum)
{
    if (threadIdx.x < 2) {
        int row = threadIdx.x, c = 0;
        for (int i = 0; i < NB; ++i) {
            int tv = bsum[row * 64 + i];
            bsum[row * 64 + i] = c;
            c += tv;
        }
    }
}

__global__ __launch_bounds__(256) void scanC(
    int* __restrict__ off, const int* __restrict__ bsum, int* __restrict__ cur)
{
    const int t = threadIdx.x, row = blockIdx.y;
    const int base = blockIdx.x * 2048 + t * 8;
    const int add = bsum[row * 64 + blockIdx.x];
    int* op = off + (size_t)row * SCN + base;
    int* cp = cur + (size_t)row * SCN + base;
    #pragma unroll
    for (int j = 0; j < 8; ++j) {
        int v = op[j] + add;
        op[j] = v;
        cp[j] = v;
    }
}

__global__ __launch_bounds__(256) void fill_adj(
    const int* __restrict__ src, const int* __restrict__ dst,
    int* __restrict__ cur, int* __restrict__ adj)
{
    int e = blockIdx.x * 256 + threadIdx.x;
    if (e >= EE) return;
    int s = src[e], d = dst[e];
    int pd = atomicAdd(&cur[d], 1);
    adj[pd] = s;
    int ps = atomicAdd(&cur[SCN + s], 1);
    adj[EE + ps] = d;
}

// ---------------- aggregation (no atomics) ----------------
__global__ __launch_bounds__(256) void aggregate(
    const int* __restrict__ off, const int* __restrict__ adj,
    const unsigned short* __restrict__ P,
    const float* __restrict__ br, const float* __restrict__ bc,
    unsigned short* __restrict__ RC)
{
    const int n    = blockIdx.x * 4 + (threadIdx.x >> 6);
    const int dir  = blockIdx.y;
    const int lane = threadIdx.x & 63;
    const int h0 = lane, h1 = lane + 64, h2 = lane + 128;

    unsigned short* outrow = RC + (size_t)n * KP + dir * 150;
    if (n >= NND) {
        outrow[h0] = 0; outrow[h1] = 0;
        if (h2 < (dir ? 170 : 150)) outrow[h2] = 0;
        return;
    }

    const int* offp = off + (size_t)dir * SCN;
    const int* adjp = adj + (size_t)dir * EE;
    const float* bias = dir ? bc : br;
    const unsigned short* own = P + (size_t)n * NPJ + dir * 300;
    const int poff = dir ? 450 : 150;

    float o0 = bf2f(own[h0]) + bias[h0];
    float o1 = bf2f(own[h1]) + bias[h1];
    float o2 = (h2 < 150) ? bf2f(own[h2]) + bias[h2] : 0.f;

    float s0 = 0.f, s1 = 0.f, s2 = 0.f;
    int beg = offp[n], end = offp[n + 1];
    for (int i = beg; i < end; ++i) {
        const unsigned short* pp = P + (size_t)adjp[i] * NPJ + poff;
        s0 += gelu_exact(o0 + bf2f(pp[h0]));
        s1 += gelu_exact(o1 + bf2f(pp[h1]));
        if (h2 < 150) s2 += gelu_exact(o2 + bf2f(pp[h2]));
    }
    outrow[h0] = f2bf(s0);
    outrow[h1] = f2bf(s1);
    if (h2 < 150)                  outrow[h2] = f2bf(s2);
    else if (dir == 1 && h2 < 170) outrow[h2] = 0;
}

// ---------------- MFMA GEMM ----------------
#define GLOAD16(gp, lp) __builtin_amdgcn_global_load_lds( \
    (const __attribute__((address_space(1))) unsigned int*)(gp), \
    (__attribute__((address_space(3))) unsigned int*)(lp), 16, 0, 0)

#define STAGE_LDS(buf, dstp, srcbase, rowoff, k0) do {                       \
    _Pragma("unroll")                                                        \
    for (int i_ = 0; i_ < 2; ++i_) {                                         \
        int cb_ = wid * 128 + i_ * 64;                                       \
        int ci_ = cb_ + lane;                                                \
        int row_ = ci_ >> 2, pc_ = ci_ & 3;                                  \
        int c_ = pc_ ^ ((row_ >> 1) & 3);                                    \
        GLOAD16(srcbase + (size_t)(rowoff + row_) * KP + (k0) + c_ * 8,      \
                &dstp[buf][cb_ * 8]);                                        \
    } } while (0)

// C[128x128 tiles] = A[M,KP](bf16) @ Bt[N,KP]^T(bf16)
// MODE 0: P[row*NPJ+col] = bf16(acc)
// MODE 1: out[row*DD+col] += gelu(acc + bias[col]); if(vbf) vbf = bf16(out)
template<int MODE>
__global__ __launch_bounds__(256) void gemm_mfma(
    const unsigned short* __restrict__ Ab,
    const unsigned short* __restrict__ Bt,
    unsigned short* __restrict__ P,
    float* __restrict__ outv, unsigned short* __restrict__ vbf,
    const float* __restrict__ bias)
{
    __shared__ char smem[32768];
    unsigned short (*Al)[4096] = (unsigned short (*)[4096])smem;
    unsigned short (*Bl)[4096] = (unsigned short (*)[4096])(smem + 16384);
    float* bounce = (float*)smem;   // 64 x 128 fp32 (reused after K-loop)

    const int tid  = threadIdx.x;
    const int lane = tid & 63;
    const int wid  = tid >> 6;

    // bijective XCD swizzle (m204)
    const int gx   = gridDim.x;
    const int nwg  = gx * gridDim.y;
    const int flat = blockIdx.y * gx + blockIdx.x;
    const int q = nwg >> 3, r = nwg & 7;
    const int xcd = flat & 7, off = flat >> 3;
    const int lid = (xcd < r ? xcd * (q + 1) : r * (q + 1) + (xcd - r) * q) + off;
    const int brow = (lid / gx) * 128;
    const int bcol = (lid % gx) * 128;

    const int wm = (wid >> 1) * 64;
    const int wn = (wid & 1) * 64;

    f32x4 acc[4][4];
    #pragma unroll
    for (int i = 0; i < 4; ++i)
        #pragma unroll
        for (int j = 0; j < 4; ++j)
            #pragma unroll
            for (int rr = 0; rr < 4; ++rr) acc[i][j][rr] = 0.f;

    // prologue: stage tile 0 (4 vmem ops per wave)
    STAGE_LDS(0, Bl, Bt, bcol, 0);
    STAGE_LDS(0, Al, Ab, brow, 0);

    int cur = 0;
    #pragma unroll
    for (int t = 0; t < NTK; ++t) {
        if (t + 1 < NTK) {
            STAGE_LDS(cur ^ 1, Bl, Bt, bcol, (t + 1) * 32);
            STAGE_LDS(cur ^ 1, Al, Ab, brow, (t + 1) * 32);
            // tile t's 4 loads done; tile t+1's 4 stay in flight (T4)
            asm volatile("s_waitcnt vmcnt(4)" ::: "memory");
        } else {
            asm volatile("s_waitcnt vmcnt(0)" ::: "memory");
        }
        __builtin_amdgcn_s_barrier();

        bf16x8 af[4], bfr[4];
        #pragma unroll
        for (int mi = 0; mi < 4; ++mi) {
            int row = wm + mi * 16 + (lane & 15);
            af[mi] = *((const bf16x8*)&Al[cur][row * 32 + (((lane >> 4) ^ ((row >> 1) & 3)) * 8)]);
        }
        #pragma unroll
        for (int nj = 0; nj < 4; ++nj) {
            int row = wn + nj * 16 + (lane & 15);
            bfr[nj] = *((const bf16x8*)&Bl[cur][row * 32 + (((lane >> 4) ^ ((row >> 1) & 3)) * 8)]);
        }
        __builtin_amdgcn_s_setprio(1);
        #pragma unroll
        for (int mi = 0; mi < 4; ++mi)
            #pragma unroll
            for (int nj = 0; nj < 4; ++nj)
                acc[mi][nj] = __builtin_amdgcn_mfma_f32_16x16x32_bf16(
                    af[mi], bfr[nj], acc[mi][nj], 0, 0, 0);
        __builtin_amdgcn_s_setprio(0);
        __builtin_amdgcn_s_barrier();   // protect buf[cur] before re-stage at t+2
        cur ^= 1;
    }

    // ---- coalesced epilogue via fp32 LDS bounce (two 64-row halves) ----
    const int ro = tid >> 5;          // 0..7
    const int co = (tid & 31) * 4;    // 0..124
    #pragma unroll
    for (int half = 0; half < 2; ++half) {
        if (wm == half * 64) {
            #pragma unroll
            for (int mi = 0; mi < 4; ++mi)
                #pragma unroll
                for (int nj = 0; nj < 4; ++nj) {
                    int lcol = wn + nj * 16 + (lane & 15);
                    int rb = mi * 16 + ((lane >> 4) << 2);
                    #pragma unroll
                    for (int rr = 0; rr < 4; ++rr)
                        bounce[(rb + rr) * 128 + lcol] = acc[mi][nj][rr];
                }
        }
        __syncthreads();
        #pragma unroll
        for (int i = 0; i < 8; ++i) {
            int lrow = ro + i * 8;
            int grow = brow + half * 64 + lrow;
            float4 vv = *(const float4*)&bounce[lrow * 128 + co];
            if (MODE == 0) {
                bf16x4 o;
                o[0] = (short)f2bf(vv.x); o[1] = (short)f2bf(vv.y);
                o[2] = (short)f2bf(vv.z); o[3] = (short)f2bf(vv.w);
                *((bf16x4*)&P[(size_t)grow * NPJ + bcol + co]) = o;
            } else if (grow < NND) {
                int gc = bcol + co;
                if (bcol < 256) {   // uniform: all 4 cols < 300
                    float4 bv = *(const float4*)&bias[gc];
                    float4 ov = *(float4*)&outv[(size_t)grow * DD + gc];
                    float4 nv;
                    nv.x = ov.x + gelu_exact(vv.x + bv.x);
                    nv.y = ov.y + gelu_exact(vv.y + bv.y);
                    nv.z = ov.z + gelu_exact(vv.z + bv.z);
                    nv.w = ov.w + gelu_exact(vv.w + bv.w);
                    *((float4*)&outv[(size_t)grow * DD + gc]) = nv;
                    if (vbf) {
                        bf16x4 o;
                        o[0] = (short)f2bf(nv.x); o[1] = (short)f2bf(nv.y);
                        o[2] = (short)f2bf(nv.z); o[3] = (short)f2bf(nv.w);
                        *((bf16x4*)&vbf[(size_t)grow * KP + gc]) = o;
                    }
                } else {
                    #pragma unroll
                    for (int j = 0; j < 4; ++j) {
                        int c = gc + j;
                        if (c < DD) {
                            float vj = (j == 0) ? vv.x : (j == 1) ? vv.y
                                     : (j == 2) ? vv.z : vv.w;
                            size_t idx = (size_t)grow * DD + c;
                            float nv = outv[idx] + gelu_exact(vj + bias[c]);
                            outv[idx] = nv;
                            if (vbf) vbf[(size_t)grow * KP + c] = f2bf(nv);
                        }
                    }
                }
            }
        }
        __syncthreads();
    }
}

extern "C" void kernel_launch(void* const* d_in, const int* in_sizes, int n_in,
                              void* d_out, int out_size, void* d_ws, size_t ws_size,
                              hipStream_t stream) {
    const float* x  = (const float*)d_in[0];
    const int*   ei = (const int*)  d_in[1];
    const float* Wr = (const float*)d_in[2];
    const float* br = (const float*)d_in[3];
    const float* Wc = (const float*)d_in[4];
    const float* bc = (const float*)d_in[5];
    const float* Wa = (const float*)d_in[6];
    const float* ba = (const float*)d_in[7];
    float* out = (float*)d_out;

    const size_t P_elems   = (size_t)MPAD * NPJ;   // bf16
    const size_t RC_elems  = (size_t)MPAD * KP;    // bf16
    const size_t V_elems   = (size_t)MPAD * KP;    // bf16
    const size_t Bt_elems  = (size_t)LL * NPJ * KP;
    const size_t Wat_elems = (size_t)NUP * KP;

    unsigned short* P   = (unsigned short*)d_ws;
    unsigned short* RC  = P + P_elems;
    unsigned short* vbf = RC + RC_elems;
    unsigned short* Bt  = vbf + V_elems;
    unsigned short* Wat = Bt + Bt_elems;
    int* deg  = (int*)(Wat + Wat_elems);
    int* off  = deg + 2 * SCN;
    int* curp = off + 2 * SCN;
    int* adj  = curp + 2 * SCN;
    int* bsum = adj + 2 * EE;
    const size_t need = (char*)(bsum + 128) - (char*)d_ws;
    if (ws_size < need) return;  // visible fail (output stays poisoned)

    hipMemcpyAsync(out, x, (size_t)NND * DD * sizeof(float),
                   hipMemcpyDeviceToDevice, stream);
    pack_w<<<2880, 256, 0, stream>>>(Wr, Wc, Wa, Bt, Wat);
    init_vbf<<<(int)((V_elems / 8 + 255) / 256), 256, 0, stream>>>(x, vbf);

    const int* src = ei;
    const int* dst = ei + EE;

    hipMemsetAsync(deg, 0, 2 * SCN * sizeof(int), stream);
    hist_deg<<<(EE + 255) / 256, 256, 0, stream>>>(src, dst, deg);
    scanA<<<dim3(NB, 2), 256, 0, stream>>>(deg, off, bsum);
    scanB<<<1, 256, 0, stream>>>(bsum);
    scanC<<<dim3(NB, 2), 256, 0, stream>>>(off, bsum, curp);
    fill_adj<<<(EE + 255) / 256, 256, 0, stream>>>(src, dst, curp, adj);

    dim3 gproj(NPJ / 128, MPAD / 128);
    dim3 gupd (NUP / 128, MPAD / 128);
    dim3 gagg (MPAD / 4, 2);

    for (int l = 0; l < LL; ++l) {
        gemm_mfma<0><<<gproj, 256, 0, stream>>>(
            vbf, Bt + (size_t)l * NPJ * KP, P, nullptr, nullptr, nullptr);
        aggregate<<<gagg, 256, 0, stream>>>(
            off, adj, P, br + (size_t)l * HH, bc + (size_t)l * HH, RC);
        gemm_mfma<1><<<gupd, 256, 0, stream>>>(
            RC, Wat, nullptr, out, (l == LL - 1) ? nullptr : vbf, ba);
    }
}

// Round 6
// 1030.139 us; speedup vs baseline: 5.2161x; 1.2465x over previous
//
#include <hip/hip_runtime.h>
#include <hip/hip_bf16.h>
#include <math.h>

#define NND 100000   // nodes
#define EE  200000   // edges
#define LL  3        // layers
#define DD  300      // node dim
#define HH  150      // per-direction message dim

#define MPAD 100096  // 782 * 128
#define KP   320     // K padded (multiple of 32)
#define NPJ  640     // proj N padded
#define NUP  384     // update N padded
#define NTK  (KP / 32)

#define NB   49          // scan blocks (2048 elems each)
#define SCN  (NB * 2048) // 100352 >= MPAD+1

typedef __attribute__((ext_vector_type(8))) short bf16x8;
typedef __attribute__((ext_vector_type(4))) short bf16x4;
typedef __attribute__((ext_vector_type(4))) float f32x4;

__device__ __forceinline__ float gelu_exact(float z) {
    return 0.5f * z * (1.0f + erff(z * 0.7071067811865475f));
}
__device__ __forceinline__ unsigned short f2bf(float f) {
    union { float fv; unsigned u; } v; v.fv = f;
    unsigned r = v.u + 0x7fff + ((v.u >> 16) & 1);   // RNE (finite inputs)
    return (unsigned short)(r >> 16);
}
__device__ __forceinline__ float bf2f(unsigned short b) {
    union { unsigned u; float fv; } v; v.u = ((unsigned)b) << 16;
    return v.fv;
}

// ---------------- weight packing ----------------
__global__ __launch_bounds__(256) void pack_w(
    const float* __restrict__ Wr, const float* __restrict__ Wc,
    const float* __restrict__ Wa,
    unsigned short* __restrict__ Bt, unsigned short* __restrict__ Wat)
{
    int i = blockIdx.x * 256 + threadIdx.x;
    const int btTotal = LL * NPJ * KP;
    if (i < btTotal) {
        int l = i / (NPJ * KP);
        int rem = i % (NPJ * KP);
        int n = rem / KP;
        int k = rem % KP;
        float v = 0.f;
        if (k < DD && n < 600) {
            const float* W = (n < 300) ? Wr : Wc;
            int nn = (n < 300) ? n : n - 300;
            int krow = (nn < 150) ? k : 300 + k;
            int j    = (nn < 150) ? nn : nn - 150;
            v = W[(size_t)l * 600 * 150 + (size_t)krow * 150 + j];
        }
        Bt[i] = f2bf(v);
    } else {
        int i2 = i - btTotal;
        if (i2 < NUP * KP) {
            int n = i2 / KP, k = i2 % KP;
            float v = (n < DD && k < DD) ? Wa[(size_t)k * DD + n] : 0.f;
            Wat[i2] = f2bf(v);
        }
    }
}

// vbf[MPAD][KP] = bf16(x), zero pads
__global__ __launch_bounds__(256) void init_vbf(
    const float* __restrict__ x, unsigned short* __restrict__ vbf)
{
    int idx = blockIdx.x * 256 + threadIdx.x;       // chunk of 8
    int row = idx / (KP / 8);
    int gk  = (idx % (KP / 8)) * 8;
    if (row >= MPAD) return;
    unsigned short tmp[8];
    if (row < NND && gk < DD) {
        if (gk + 8 <= DD) {
            const float4* p = (const float4*)(x + (size_t)row * DD + gk);
            float4 f0 = p[0], f1 = p[1];
            tmp[0] = f2bf(f0.x); tmp[1] = f2bf(f0.y);
            tmp[2] = f2bf(f0.z); tmp[3] = f2bf(f0.w);
            tmp[4] = f2bf(f1.x); tmp[5] = f2bf(f1.y);
            tmp[6] = f2bf(f1.z); tmp[7] = f2bf(f1.w);
        } else {
            #pragma unroll
            for (int j = 0; j < 8; ++j)
                tmp[j] = (gk + j < DD) ? f2bf(x[(size_t)row * DD + gk + j]) : 0;
        }
    } else {
        #pragma unroll
        for (int j = 0; j < 8; ++j) tmp[j] = 0;
    }
    *((bf16x8*)&vbf[(size_t)row * KP + gk]) = *((bf16x8*)tmp);
}

// ---------------- CSR build ----------------
__global__ __launch_bounds__(256) void hist_deg(
    const int* __restrict__ src, const int* __restrict__ dst,
    int* __restrict__ deg)
{
    int e = blockIdx.x * 256 + threadIdx.x;
    if (e >= EE) return;
    atomicAdd(&deg[dst[e]], 1);
    atomicAdd(&deg[SCN + src[e]], 1);
}

__global__ __launch_bounds__(256) void scanA(
    const int* __restrict__ deg, int* __restrict__ off, int* __restrict__ bsum)
{
    __shared__ int ls[256];
    const int t = threadIdx.x, row = blockIdx.y;
    const int base = blockIdx.x * 2048 + t * 8;
    const int* dg = deg + (size_t)row * SCN + base;
    int v[8];
    #pragma unroll
    for (int j = 0; j < 8; ++j) v[j] = dg[j];
    int tot = 0;
    #pragma unroll
    for (int j = 0; j < 8; ++j) tot += v[j];
    ls[t] = tot;
    __syncthreads();
    #pragma unroll
    for (int d = 1; d < 256; d <<= 1) {
        int tv = (t >= d) ? ls[t - d] : 0;
        __syncthreads();
        ls[t] += tv;
        __syncthreads();
    }
    int run = ls[t] - tot;
    int* op = off + (size_t)row * SCN + base;
    #pragma unroll
    for (int j = 0; j < 8; ++j) { op[j] = run; run += v[j]; }
    if (t == 255) bsum[row * 64 + blockIdx.x] = ls[255];
}

__global__ __launch_bounds__(256) void scanB(int* __restrict__ bsum)
{
    if (threadIdx.x < 2) {
        int row = threadIdx.x, c = 0;
        for (int i = 0; i < NB; ++i) {
            int tv = bsum[row * 64 + i];
            bsum[row * 64 + i] = c;
            c += tv;
        }
    }
}

__global__ __launch_bounds__(256) void scanC(
    int* __restrict__ off, const int* __restrict__ bsum, int* __restrict__ cur)
{
    const int t = threadIdx.x, row = blockIdx.y;
    const int base = blockIdx.x * 2048 + t * 8;
    const int add = bsum[row * 64 + blockIdx.x];
    int* op = off + (size_t)row * SCN + base;
    int* cp = cur + (size_t)row * SCN + base;
    #pragma unroll
    for (int j = 0; j < 8; ++j) {
        int v = op[j] + add;
        op[j] = v;
        cp[j] = v;
    }
}

__global__ __launch_bounds__(256) void fill_adj(
    const int* __restrict__ src, const int* __restrict__ dst,
    int* __restrict__ cur, int* __restrict__ adj)
{
    int e = blockIdx.x * 256 + threadIdx.x;
    if (e >= EE) return;
    int s = src[e], d = dst[e];
    int pd = atomicAdd(&cur[d], 1);
    adj[pd] = s;
    int ps = atomicAdd(&cur[SCN + s], 1);
    adj[EE + ps] = d;
}

// ---------------- aggregation (no atomics) ----------------
__global__ __launch_bounds__(256) void aggregate(
    const int* __restrict__ off, const int* __restrict__ adj,
    const unsigned short* __restrict__ P,
    const float* __restrict__ br, const float* __restrict__ bc,
    unsigned short* __restrict__ RC)
{
    const int n    = blockIdx.x * 4 + (threadIdx.x >> 6);
    const int dir  = blockIdx.y;
    const int lane = threadIdx.x & 63;
    const int h0 = lane, h1 = lane + 64, h2 = lane + 128;

    unsigned short* outrow = RC + (size_t)n * KP + dir * 150;
    if (n >= NND) {
        outrow[h0] = 0; outrow[h1] = 0;
        if (h2 < (dir ? 170 : 150)) outrow[h2] = 0;
        return;
    }

    const int* offp = off + (size_t)dir * SCN;
    const int* adjp = adj + (size_t)dir * EE;
    const float* bias = dir ? bc : br;
    const unsigned short* own = P + (size_t)n * NPJ + dir * 300;
    const int poff = dir ? 450 : 150;

    float o0 = bf2f(own[h0]) + bias[h0];
    float o1 = bf2f(own[h1]) + bias[h1];
    float o2 = (h2 < 150) ? bf2f(own[h2]) + bias[h2] : 0.f;

    float s0 = 0.f, s1 = 0.f, s2 = 0.f;
    int beg = offp[n], end = offp[n + 1];
    for (int i = beg; i < end; ++i) {
        const unsigned short* pp = P + (size_t)adjp[i] * NPJ + poff;
        s0 += gelu_exact(o0 + bf2f(pp[h0]));
        s1 += gelu_exact(o1 + bf2f(pp[h1]));
        if (h2 < 150) s2 += gelu_exact(o2 + bf2f(pp[h2]));
    }
    outrow[h0] = f2bf(s0);
    outrow[h1] = f2bf(s1);
    if (h2 < 150)                  outrow[h2] = f2bf(s2);
    else if (dir == 1 && h2 < 170) outrow[h2] = 0;
}

// ---------------- MFMA GEMM (3-deep pipeline) ----------------
#define GLOAD16(gp, lp) __builtin_amdgcn_global_load_lds( \
    (const __attribute__((address_space(1))) unsigned int*)(gp), \
    (__attribute__((address_space(3))) unsigned int*)(lp), 16, 0, 0)

#define STAGE_LDS(dstp, srcbase, rowoff, k0) do {                            \
    _Pragma("unroll")                                                        \
    for (int i_ = 0; i_ < 2; ++i_) {                                         \
        int cb_ = wid * 128 + i_ * 64;                                       \
        int ci_ = cb_ + lane;                                                \
        int row_ = ci_ >> 2, pc_ = ci_ & 3;                                  \
        int c_ = pc_ ^ ((row_ >> 1) & 3);                                    \
        GLOAD16(srcbase + (size_t)(rowoff + row_) * KP + (k0) + c_ * 8,      \
                &(dstp)[cb_ * 8]);                                           \
    } } while (0)

// C[128x128 tiles] = A[M,KP](bf16) @ Bt[N,KP]^T(bf16)
// MODE 0: P[row*NPJ+col] = bf16(acc)
// MODE 1: nv = vbf_old + gelu(acc + bias[col]); last? out=fp32(nv) : vbf=bf16(nv)
template<int MODE>
__global__ __launch_bounds__(256) void gemm_mfma(
    const unsigned short* __restrict__ Ab,
    const unsigned short* __restrict__ Bt,
    unsigned short* __restrict__ P,
    float* __restrict__ outv, unsigned short* __restrict__ vbf,
    const float* __restrict__ bias, int last)
{
    __shared__ char smem[49152];   // 3 x (A 8KB + B 8KB)
    float* bounce = (float*)smem;  // 64 x 128 fp32, reused after K-loop

    const int tid  = threadIdx.x;
    const int lane = tid & 63;
    const int wid  = tid >> 6;

    // bijective XCD swizzle (m204)
    const int gx   = gridDim.x;
    const int nwg  = gx * gridDim.y;
    const int flat = blockIdx.y * gx + blockIdx.x;
    const int q = nwg >> 3, r = nwg & 7;
    const int xcd = flat & 7, off = flat >> 3;
    const int lid = (xcd < r ? xcd * (q + 1) : r * (q + 1) + (xcd - r) * q) + off;
    const int brow = (lid / gx) * 128;
    const int bcol = (lid % gx) * 128;

    const int wm = (wid >> 1) * 64;
    const int wn = (wid & 1) * 64;

    f32x4 acc[4][4];
    #pragma unroll
    for (int i = 0; i < 4; ++i)
        #pragma unroll
        for (int j = 0; j < 4; ++j)
            #pragma unroll
            for (int rr = 0; rr < 4; ++rr) acc[i][j][rr] = 0.f;

    // prologue: stage tiles 0 and 1 (4 vmem ops per wave per tile)
    #pragma unroll
    for (int t = 0; t < 2; ++t) {
        unsigned short* Al = (unsigned short*)(smem + t * 16384);
        unsigned short* Bl = (unsigned short*)(smem + t * 16384 + 8192);
        STAGE_LDS(Al, Ab, brow, t * 32);
        STAGE_LDS(Bl, Bt, bcol, t * 32);
    }

    #pragma unroll
    for (int t = 0; t < NTK; ++t) {
        const int b  = t % 3;
        unsigned short* Alc = (unsigned short*)(smem + b * 16384);
        unsigned short* Blc = (unsigned short*)(smem + b * 16384 + 8192);
        if (t + 2 < NTK) {
            const int bn = (t + 2) % 3;
            unsigned short* Aln = (unsigned short*)(smem + bn * 16384);
            unsigned short* Bln = (unsigned short*)(smem + bn * 16384 + 8192);
            STAGE_LDS(Aln, Ab, brow, (t + 2) * 32);
            STAGE_LDS(Bln, Bt, bcol, (t + 2) * 32);
            // tile t's 4 loads done; tiles t+1,t+2 (8 loads) stay in flight
            asm volatile("s_waitcnt vmcnt(8)" ::: "memory");
        } else if (t + 1 < NTK) {
            asm volatile("s_waitcnt vmcnt(4)" ::: "memory");
        } else {
            asm volatile("s_waitcnt vmcnt(0)" ::: "memory");
        }
        __builtin_amdgcn_s_barrier();

        bf16x8 af[4], bfr[4];
        #pragma unroll
        for (int mi = 0; mi < 4; ++mi) {
            int row = wm + mi * 16 + (lane & 15);
            af[mi] = *((const bf16x8*)&Alc[row * 32 + (((lane >> 4) ^ ((row >> 1) & 3)) * 8)]);
        }
        #pragma unroll
        for (int nj = 0; nj < 4; ++nj) {
            int row = wn + nj * 16 + (lane & 15);
            bfr[nj] = *((const bf16x8*)&Blc[row * 32 + (((lane >> 4) ^ ((row >> 1) & 3)) * 8)]);
        }
        __builtin_amdgcn_s_setprio(1);
        #pragma unroll
        for (int mi = 0; mi < 4; ++mi)
            #pragma unroll
            for (int nj = 0; nj < 4; ++nj)
                acc[mi][nj] = __builtin_amdgcn_mfma_f32_16x16x32_bf16(
                    af[mi], bfr[nj], acc[mi][nj], 0, 0, 0);
        __builtin_amdgcn_s_setprio(0);
        __builtin_amdgcn_s_barrier();   // protect buf before re-stage
    }

    // ---- coalesced epilogue via fp32 LDS bounce (two 64-row halves) ----
    const int ro = tid >> 5;          // 0..7
    const int co = (tid & 31) * 4;    // 0..124
    #pragma unroll
    for (int half = 0; half < 2; ++half) {
        if (wm == half * 64) {
            #pragma unroll
            for (int mi = 0; mi < 4; ++mi)
                #pragma unroll
                for (int nj = 0; nj < 4; ++nj) {
                    int lcol = wn + nj * 16 + (lane & 15);
                    int rb = mi * 16 + ((lane >> 4) << 2);
                    #pragma unroll
                    for (int rr = 0; rr < 4; ++rr)
                        bounce[(rb + rr) * 128 + lcol] = acc[mi][nj][rr];
                }
        }
        __syncthreads();
        #pragma unroll
        for (int i = 0; i < 8; ++i) {
            int lrow = ro + i * 8;
            int grow = brow + half * 64 + lrow;
            float4 vv = *(const float4*)&bounce[lrow * 128 + co];
            if (MODE == 0) {
                bf16x4 o;
                o[0] = (short)f2bf(vv.x); o[1] = (short)f2bf(vv.y);
                o[2] = (short)f2bf(vv.z); o[3] = (short)f2bf(vv.w);
                *((bf16x4*)&P[(size_t)grow * NPJ + bcol + co]) = o;
            } else if (grow < NND) {
                int gc = bcol + co;
                if (bcol < 256) {   // uniform: all 4 cols < 300
                    float4 bv = *(const float4*)&bias[gc];
                    bf16x4 old = *(const bf16x4*)&vbf[(size_t)grow * KP + gc];
                    float4 nv;
                    nv.x = bf2f((unsigned short)old[0]) + gelu_exact(vv.x + bv.x);
                    nv.y = bf2f((unsigned short)old[1]) + gelu_exact(vv.y + bv.y);
                    nv.z = bf2f((unsigned short)old[2]) + gelu_exact(vv.z + bv.z);
                    nv.w = bf2f((unsigned short)old[3]) + gelu_exact(vv.w + bv.w);
                    if (last) {
                        *((float4*)&outv[(size_t)grow * DD + gc]) = nv;
                    } else {
                        bf16x4 o;
                        o[0] = (short)f2bf(nv.x); o[1] = (short)f2bf(nv.y);
                        o[2] = (short)f2bf(nv.z); o[3] = (short)f2bf(nv.w);
                        *((bf16x4*)&vbf[(size_t)grow * KP + gc]) = o;
                    }
                } else {
                    #pragma unroll
                    for (int j = 0; j < 4; ++j) {
                        int c = gc + j;
                        if (c < DD) {
                            float vj = (j == 0) ? vv.x : (j == 1) ? vv.y
                                     : (j == 2) ? vv.z : vv.w;
                            size_t vidx = (size_t)grow * KP + c;
                            float nv = bf2f(vbf[vidx]) + gelu_exact(vj + bias[c]);
                            if (last) outv[(size_t)grow * DD + c] = nv;
                            else      vbf[vidx] = f2bf(nv);
                        }
                    }
                }
            }
        }
        __syncthreads();
    }
}

extern "C" void kernel_launch(void* const* d_in, const int* in_sizes, int n_in,
                              void* d_out, int out_size, void* d_ws, size_t ws_size,
                              hipStream_t stream) {
    const float* x  = (const float*)d_in[0];
    const int*   ei = (const int*)  d_in[1];
    const float* Wr = (const float*)d_in[2];
    const float* br = (const float*)d_in[3];
    const float* Wc = (const float*)d_in[4];
    const float* bc = (const float*)d_in[5];
    const float* Wa = (const float*)d_in[6];
    const float* ba = (const float*)d_in[7];
    float* out = (float*)d_out;

    const size_t P_elems   = (size_t)MPAD * NPJ;   // bf16
    const size_t RC_elems  = (size_t)MPAD * KP;    // bf16
    const size_t V_elems   = (size_t)MPAD * KP;    // bf16
    const size_t Bt_elems  = (size_t)LL * NPJ * KP;
    const size_t Wat_elems = (size_t)NUP * KP;

    unsigned short* P   = (unsigned short*)d_ws;
    unsigned short* RC  = P + P_elems;
    unsigned short* vbf = RC + RC_elems;
    unsigned short* Bt  = vbf + V_elems;
    unsigned short* Wat = Bt + Bt_elems;
    int* deg  = (int*)(Wat + Wat_elems);
    int* off  = deg + 2 * SCN;
    int* curp = off + 2 * SCN;
    int* adj  = curp + 2 * SCN;
    int* bsum = adj + 2 * EE;
    const size_t need = (char*)(bsum + 128) - (char*)d_ws;
    if (ws_size < need) return;  // visible fail (output stays poisoned)

    pack_w<<<2880, 256, 0, stream>>>(Wr, Wc, Wa, Bt, Wat);
    init_vbf<<<(int)((V_elems / 8 + 255) / 256), 256, 0, stream>>>(x, vbf);

    const int* src = ei;
    const int* dst = ei + EE;

    hipMemsetAsync(deg, 0, 2 * SCN * sizeof(int), stream);
    hist_deg<<<(EE + 255) / 256, 256, 0, stream>>>(src, dst, deg);
    scanA<<<dim3(NB, 2), 256, 0, stream>>>(deg, off, bsum);
    scanB<<<1, 256, 0, stream>>>(bsum);
    scanC<<<dim3(NB, 2), 256, 0, stream>>>(off, bsum, curp);
    fill_adj<<<(EE + 255) / 256, 256, 0, stream>>>(src, dst, curp, adj);

    dim3 gproj(NPJ / 128, MPAD / 128);
    dim3 gupd (NUP / 128, MPAD / 128);
    dim3 gagg (MPAD / 4, 2);

    for (int l = 0; l < LL; ++l) {
        gemm_mfma<0><<<gproj, 256, 0, stream>>>(
            vbf, Bt + (size_t)l * NPJ * KP, P, nullptr, nullptr, nullptr, 0);
        aggregate<<<gagg, 256, 0, stream>>>(
            off, adj, P, br + (size_t)l * HH, bc + (size_t)l * HH, RC);
        gemm_mfma<1><<<gupd, 256, 0, stream>>>(
            RC, Wat, nullptr, out, vbf, ba, (l == LL - 1) ? 1 : 0);
    }
}